// Round 6
// baseline (139.606 us; speedup 1.0000x reference)
//
#include <hip/hip_runtime.h>
#include <hip/hip_bf16.h>

// Joiner: out[b,t,u,v] = tanh(enc[b,t,:] + pred[b,u,:]) . W[v,:] + bias[v]
// B=8 T=512 U=128 D=256 V=128, fp32 in/out.
// Block = (b, 16-t chunk, u-half of 64), 512 thr = 8 waves in a 2u x 4v grid;
// each wave owns a 32u x 32v output sub-tile -> joint-tile LDS reads halve vs
// the 16v-per-wave layout, and each wave writes full 128B lines.
// pred + W + bias persist in registers. tanh tile double-buffered in
// XOR-swizzled LDS; one s_barrier/iter with lgkmcnt-only wait (stores never
// drained in-loop).

constexpr int Bn = 8, Tn = 512, Un = 128, Dn = 256, Vn = 128;
constexpr int TCHUNK = 16;

typedef __attribute__((ext_vector_type(8))) short bf16x8;   // 8 bf16 = 4 VGPRs
typedef __attribute__((ext_vector_type(4))) float f32x4;
typedef __attribute__((ext_vector_type(4))) unsigned int u32x4;

static __device__ __forceinline__ unsigned short f2bf(float f) {
    unsigned int u = __float_as_uint(f);
    return (unsigned short)((u + 0x7fffu + ((u >> 16) & 1u)) >> 16);
}
static __device__ __forceinline__ float bf2f(unsigned short h) {
    return __uint_as_float(((unsigned int)h) << 16);
}
// pack 2 f32 -> 2 bf16 (RNE) in one instruction
static __device__ __forceinline__ unsigned int cvt_pk_bf16(float lo, float hi) {
    unsigned int r;
    asm volatile("v_cvt_pk_bf16_f32 %0, %1, %2" : "=v"(r) : "v"(lo), "v"(hi));
    return r;
}
// tanh(x) = 1 - 2/(exp2(x*2*log2e)+1); med3 clamp; 3 VALU + 2 trans
static __device__ __forceinline__ float fast_tanh(float x) {
    float t = __builtin_amdgcn_fmed3f(x, -8.f, 8.f);
    float e = __builtin_amdgcn_exp2f(2.8853900817779268f * t);
    float r = __builtin_amdgcn_rcpf(e + 1.f);
    return __builtin_fmaf(-2.f, r, 1.f);
}

__global__ __launch_bounds__(256) void cvtW_kernel(const float* __restrict__ W,
                                                   unsigned short* __restrict__ Wb) {
    int i = blockIdx.x * 256 + threadIdx.x;          // 32 blocks * 256 * 4 elems = 32768
    float4 v = ((const float4*)W)[i];
    unsigned short r0 = f2bf(v.x), r1 = f2bf(v.y), r2 = f2bf(v.z), r3 = f2bf(v.w);
    unsigned long long packed = (unsigned long long)r0 | ((unsigned long long)r1 << 16) |
                                ((unsigned long long)r2 << 32) | ((unsigned long long)r3 << 48);
    ((unsigned long long*)Wb)[i] = packed;
}

__global__ __launch_bounds__(512, 4) void joiner_kernel(
    const float* __restrict__ enc,         // [B,T,D]
    const float* __restrict__ pred,        // [B,U,D]
    const unsigned short* __restrict__ Wb, // [V,D] bf16 bits
    const float* __restrict__ bias,        // [V]
    float* __restrict__ out)               // [B,T,U,V]
{
    // joint tile: 64 u-rows x 256 d (bf16) as 16B granules, granule ^= (row&7)
    // swizzle (conflict-free writes AND reads; 0 conflicts measured R2/R4).
    __shared__ unsigned short jointS[2][64 * 256];   // 2 x 32 KB

    const int bid = blockIdx.x;            // (b*32 + tc)*2 + uh
    const int uh  = bid & 1;
    const int tc  = (bid >> 1) & 31;
    const int b   = bid >> 6;
    const int tid = threadIdx.x;
    const int w   = tid >> 6;              // 8 waves: wv = w&3 (v 32-col), wu = w>>2 (u 32-row)
    const int wv  = w & 3;
    const int wu  = w >> 2;
    const int l16 = tid & 15;
    const int lq  = (tid >> 4) & 3;

    // phase-1 static mapping: thread owns rows {ub, ub+32} x 16 d at d0=db*16
    const int db = tid & 15;
    const int ub = tid >> 4;               // 0..31

    // ---- persistent state (loaded once per block) ----
    bf16x8 predR[2][2];                    // 2 rows x 16 d, bf16 (16 VGPR)
#pragma unroll
    for (int j = 0; j < 2; ++j) {
        const float* pr = pred + ((size_t)(b * Un + uh * 64 + ub + 32 * j)) * Dn + db * 16;
        float4 a0 = *(const float4*)(pr + 0);
        float4 a1 = *(const float4*)(pr + 4);
        float4 a2 = *(const float4*)(pr + 8);
        float4 a3 = *(const float4*)(pr + 12);
        bf16x8 q0, q1;
        q0[0] = (short)f2bf(a0.x); q0[1] = (short)f2bf(a0.y);
        q0[2] = (short)f2bf(a0.z); q0[3] = (short)f2bf(a0.w);
        q0[4] = (short)f2bf(a1.x); q0[5] = (short)f2bf(a1.y);
        q0[6] = (short)f2bf(a1.z); q0[7] = (short)f2bf(a1.w);
        q1[0] = (short)f2bf(a2.x); q1[1] = (short)f2bf(a2.y);
        q1[2] = (short)f2bf(a2.z); q1[3] = (short)f2bf(a2.w);
        q1[4] = (short)f2bf(a3.x); q1[5] = (short)f2bf(a3.y);
        q1[6] = (short)f2bf(a3.z); q1[7] = (short)f2bf(a3.w);
        predR[j][0] = q0; predR[j][1] = q1;
    }

    // W A-frags: this wave's 32 v rows (2 n-tiles) x K=256 -> 16 x bf16x8 (64 VGPR)
    bf16x8 wfr[8][2];
#pragma unroll
    for (int kk = 0; kk < 8; ++kk)
#pragma unroll
        for (int n = 0; n < 2; ++n)
            wfr[kk][n] = *(const bf16x8*)(Wb + (size_t)(wv * 32 + n * 16 + l16) * Dn
                                          + kk * 32 + lq * 8);

    float4 bv[2];
#pragma unroll
    for (int n = 0; n < 2; ++n)
        bv[n] = *(const float4*)(bias + wv * 32 + n * 16 + lq * 4);

    const size_t encBase = (size_t)(b * Tn + tc * TCHUNK) * Dn;

    // tanh(enc + pred) -> swizzled LDS tile (each value computed exactly once)
    auto write_tile = [&](unsigned short* buf, const float ev[16]) {
#pragma unroll
        for (int j = 0; j < 2; ++j) {
            const int r  = ub + 32 * j;
            const int sw = r & 7;
            float t[16];
#pragma unroll
            for (int i = 0; i < 8; ++i)
                t[i] = fast_tanh(ev[i] + bf2f((unsigned short)predR[j][0][i]));
#pragma unroll
            for (int i = 0; i < 8; ++i)
                t[8 + i] = fast_tanh(ev[8 + i] + bf2f((unsigned short)predR[j][1][i]));
            u32x4 q0, q1;
#pragma unroll
            for (int k = 0; k < 4; ++k) q0[k] = cvt_pk_bf16(t[2 * k], t[2 * k + 1]);
#pragma unroll
            for (int k = 0; k < 4; ++k) q1[k] = cvt_pk_bf16(t[8 + 2 * k], t[9 + 2 * k]);
            *(u32x4*)&buf[((r * 32) + ((db * 2) ^ sw)) * 8]     = q0;
            *(u32x4*)&buf[((r * 32) + ((db * 2 + 1) ^ sw)) * 8] = q1;
        }
    };
    auto load_enc = [&](int t_idx, float ev[16]) {
        const float* er = enc + encBase + (size_t)t_idx * Dn + db * 16;
        float4 a0 = *(const float4*)(er + 0);
        float4 a1 = *(const float4*)(er + 4);
        float4 a2 = *(const float4*)(er + 8);
        float4 a3 = *(const float4*)(er + 12);
        ev[0] = a0.x;  ev[1] = a0.y;  ev[2]  = a0.z;  ev[3]  = a0.w;
        ev[4] = a1.x;  ev[5] = a1.y;  ev[6]  = a1.z;  ev[7]  = a1.w;
        ev[8] = a2.x;  ev[9] = a2.y;  ev[10] = a2.z;  ev[11] = a2.w;
        ev[12] = a3.x; ev[13] = a3.y; ev[14] = a3.z;  ev[15] = a3.w;
    };

    // ---- prologue: tile 0 into buf 0 ----
    {
        float ev[16];
        load_enc(0, ev);
        write_tile(jointS[0], ev);
    }
    asm volatile("s_waitcnt lgkmcnt(0)" ::: "memory");
    __builtin_amdgcn_s_barrier();
    __builtin_amdgcn_sched_barrier(0);

    for (int ti = 0; ti < TCHUNK; ++ti) {
        const unsigned short* cur = jointS[ti & 1];

        // ---------- MFMA: A = W regs (32 v), B = joint tile (32 u) ----------
        f32x4 acc[2][2];                   // [ut][n]
#pragma unroll
        for (int ut = 0; ut < 2; ++ut)
#pragma unroll
            for (int n = 0; n < 2; ++n) acc[ut][n] = (f32x4){0.f, 0.f, 0.f, 0.f};

#pragma unroll
        for (int kk = 0; kk < 8; ++kk) {
            bf16x8 bfr[2];
#pragma unroll
            for (int ut = 0; ut < 2; ++ut) {
                const int row = wu * 32 + ut * 16 + l16;
                bfr[ut] = *(const bf16x8*)&cur[((row * 32) + ((kk * 4 + lq) ^ (l16 & 7))) * 8];
            }
#pragma unroll
            for (int ut = 0; ut < 2; ++ut)
#pragma unroll
                for (int n = 0; n < 2; ++n)
                    acc[ut][n] = __builtin_amdgcn_mfma_f32_16x16x32_bf16(
                        wfr[kk][n], bfr[ut], acc[ut][n], 0, 0, 0);
        }

        // ---------- epilogue: bias + float4 stores (full 128B lines/wave) ----------
        const size_t rowBase = (size_t)((b * Tn + tc * TCHUNK + ti) * Un + uh * 64);
#pragma unroll
        for (int ut = 0; ut < 2; ++ut) {
            float* ob = out + (rowBase + wu * 32 + ut * 16 + l16) * Vn + wv * 32 + lq * 4;
#pragma unroll
            for (int n = 0; n < 2; ++n) {
                f32x4 rv;
                rv[0] = acc[ut][n][0] + bv[n].x;
                rv[1] = acc[ut][n][1] + bv[n].y;
                rv[2] = acc[ut][n][2] + bv[n].z;
                rv[3] = acc[ut][n][3] + bv[n].w;
                *(f32x4*)(ob + n * 16) = rv;
            }
        }

        // ---------- next tanh tile into the other buffer ----------
        if (ti + 1 < TCHUNK) {
            float ev[16];
            load_enc(ti + 1, ev);          // L1/L2-hot; latency overlapped by other waves
            write_tile(jointS[(ti + 1) & 1], ev);
            // barrier protects LDS only: wait ds ops, NOT the global stores
            asm volatile("s_waitcnt lgkmcnt(0)" ::: "memory");
            __builtin_amdgcn_s_barrier();
            __builtin_amdgcn_sched_barrier(0);
        }
    }
}

extern "C" void kernel_launch(void* const* d_in, const int* in_sizes, int n_in,
                              void* d_out, int out_size, void* d_ws, size_t ws_size,
                              hipStream_t stream) {
    const float* enc  = (const float*)d_in[0];
    const float* pred = (const float*)d_in[1];
    const float* W    = (const float*)d_in[2];
    const float* bias = (const float*)d_in[3];
    float* out = (float*)d_out;
    unsigned short* Wb = (unsigned short*)d_ws;   // 32768 bf16 = 64 KB

    cvtW_kernel<<<32, 256, 0, stream>>>(W, Wb);
    // grid = B * (T/TCHUNK) * 2 u-halves = 8 * 32 * 2 = 512 blocks
    joiner_kernel<<<512, 512, 0, stream>>>(enc, pred, Wb, bias, out);
}